// Round 11
// baseline (280.374 us; speedup 1.0000x reference)
//
#include <hip/hip_runtime.h>

// QuantizedLinear: out[t][o] = sum_k x[t][k] * (w_q[o][k]-128)*scale[o] + bias[o]
// M=16, N=8192, K=8192. Memory-bound on w_q (256 MB int32, read once).
//
// R11 = R6 (best, 75.7us: barrier-free monolithic stream, no LDS) with two
// latency-hiding fixes, per-wave economics unchanged (W_O=4):
//  1. BLOCK=128 (2 waves), grid=1024 -> 4 blocks/CU = 4 waves/SIMD (R6 had 2).
//     More resident waves = more w-bytes in flight per CU.
//  2. Nontemporal (nt) w loads: w is single-use; keep it from evicting x
//     from L2 so x stays L2-hot (R10 counters showed ~141 MB x refetch).
// R9/R10 lesson: NO manual prefetch/reg-staging -- in-order vmcnt makes any
// consume drain everything issued before its producer; compiler's unroll-2
// schedule is already minimal-wait.

#define IN_F   8192
#define OUT_F  8192
#define NT     16
#define BLOCK  128
#define W_O    4
#define CH_PER_BLOCK 8     // 2 waves * W_O
#define NSTEP  (IN_F / 256)  // 32

typedef int i4x __attribute__((ext_vector_type(4)));

__global__ __launch_bounds__(BLOCK, 4)
void qlin_kernel(const float* __restrict__ x,     // [16][8192]
                 const int*   __restrict__ w_q,   // [8192][8192]
                 const float* __restrict__ scale, // [8192]
                 const float* __restrict__ bias,  // [8192]
                 float* __restrict__ out)         // [16][8192]
{
    const int tid  = threadIdx.x;
    const int lane = tid & 63;
    const int wave = tid >> 6;
    const int o_base = blockIdx.x * CH_PER_BLOCK + wave * W_O;

    const i4x* __restrict__ wr0 = (const i4x*)(w_q + (size_t)(o_base + 0) * IN_F);
    const i4x* __restrict__ wr1 = (const i4x*)(w_q + (size_t)(o_base + 1) * IN_F);
    const i4x* __restrict__ wr2 = (const i4x*)(w_q + (size_t)(o_base + 2) * IN_F);
    const i4x* __restrict__ wr3 = (const i4x*)(w_q + (size_t)(o_base + 3) * IN_F);

    float acc[NT][W_O];
#pragma unroll
    for (int t = 0; t < NT; ++t)
#pragma unroll
        for (int j = 0; j < W_O; ++j) acc[t][j] = 0.0f;

    // 32 k-steps; each covers 256 k (64 lanes x 4 ints). No barriers, no LDS.
#pragma unroll 2
    for (int ks = 0; ks < NSTEP; ++ks) {
        const int kq = ks * 64 + lane;            // int4 index within row
        const int k  = ks * 256 + lane * 4;       // element index

        const i4x w0 = __builtin_nontemporal_load(wr0 + kq);
        const i4x w1 = __builtin_nontemporal_load(wr1 + kq);
        const i4x w2 = __builtin_nontemporal_load(wr2 + kq);
        const i4x w3 = __builtin_nontemporal_load(wr3 + kq);

        float wf[W_O][4];
#pragma unroll
        for (int e = 0; e < 4; ++e) {
            wf[0][e] = (float)(w0[e] - 128);
            wf[1][e] = (float)(w1[e] - 128);
            wf[2][e] = (float)(w2[e] - 128);
            wf[3][e] = (float)(w3[e] - 128);
        }

#pragma unroll
        for (int t = 0; t < NT; ++t) {
            const float4 xv = *reinterpret_cast<const float4*>(
                &x[(size_t)t * IN_F + k]);        // L2-hot (nt keeps it so)
#pragma unroll
            for (int j = 0; j < W_O; ++j) {
                acc[t][j] += wf[j][0] * xv.x;
                acc[t][j] += wf[j][1] * xv.y;
                acc[t][j] += wf[j][2] * xv.z;
                acc[t][j] += wf[j][3] * xv.w;
            }
        }
    }

    // ---- cross-lane reduction: 64 (t,j) values, 6-step butterfly each ----
    float myval = 0.0f;
#pragma unroll
    for (int t = 0; t < NT; ++t) {
#pragma unroll
        for (int j = 0; j < W_O; ++j) {
            float v = acc[t][j];
#pragma unroll
            for (int off = 32; off > 0; off >>= 1)
                v += __shfl_xor(v, off, 64);
            if (lane == (t * W_O + j)) myval = v;
        }
    }

    // lane l -> (t = l>>2, channel j = l&3)
    const int t_o = lane >> 2;
    const int o   = o_base + (lane & 3);
    out[(size_t)t_o * OUT_F + o] = myval * scale[o] + bias[o];
}

extern "C" void kernel_launch(void* const* d_in, const int* in_sizes, int n_in,
                              void* d_out, int out_size, void* d_ws, size_t ws_size,
                              hipStream_t stream) {
    const float* x     = (const float*)d_in[0];
    const int*   w_q   = (const int*)d_in[1];
    const float* scale = (const float*)d_in[2];
    const float* bias  = (const float*)d_in[3];
    float*       out   = (float*)d_out;

    dim3 grid(OUT_F / CH_PER_BLOCK);   // 1024 blocks -> 4 per CU, 4 waves/SIMD
    dim3 block(BLOCK);
    qlin_kernel<<<grid, block, 0, stream>>>(x, w_q, scale, bias, out);
}

// Round 12
// 64.591 us; speedup vs baseline: 4.3408x; 4.3408x over previous
//
#include <hip/hip_runtime.h>

// QuantizedLinear: out[t][o] = sum_k x[t][k] * (w_q[o][k]-128)*scale[o] + bias[o]
// M=16, N=8192, K=8192. Memory-bound on w_q (256 MB int32, read once).
//
// R12 = R6 stream + x staged in LDS via global_load_lds (VGPR-free staging,
// fixes R10's spill) + raw s_barrier (no vmcnt(0) drain, fixes R1) + packed
// f32 FMA (halves dominant VALU term; VALU/byte was ~93% of SIMD at full BW).
// Ordering contract: STAGE(c+1) is issued BEFORE chunk c's w-loads
// (sched_barrier(0) fences); in-order vmcnt retirement of chunk-c w-loads
// (consumed by FMAs before the barrier) then implies stage completion --
// no explicit vmcnt wait needed, w-stream never drained mid-kernel.
// VGPR budget: launch_bounds(256,2) -> 256 cap; acc2=64 + working ~70. No cap
// below ~170 is safe (R11: cap 64 spilled acc, 274 MB scratch writes).

#define IN_F   8192
#define OUT_F  8192
#define NT     16
#define BLOCK  256
#define W_O    4
#define CH_PER_BLOCK 16          // 4 waves * W_O
#define K_CHUNK 512
#define NCHUNK (IN_F / K_CHUNK)  // 16

typedef float f32x2 __attribute__((ext_vector_type(2)));

__global__ __launch_bounds__(BLOCK, 2)
void qlin_kernel(const float* __restrict__ x,     // [16][8192]
                 const int*   __restrict__ w_q,   // [8192][8192]
                 const float* __restrict__ scale, // [8192]
                 const float* __restrict__ bias,  // [8192]
                 float* __restrict__ out)         // [16][8192]
{
    __shared__ float xs[2][NT][K_CHUNK];          // 64 KB -> 2 blocks/CU

    const int tid  = threadIdx.x;
    const int lane = tid & 63;
    const int wave = tid >> 6;
    const int o_base = blockIdx.x * CH_PER_BLOCK + wave * W_O;

    const int* __restrict__ wr0 = w_q + (size_t)(o_base + 0) * IN_F;
    const int* __restrict__ wr1 = w_q + (size_t)(o_base + 1) * IN_F;
    const int* __restrict__ wr2 = w_q + (size_t)(o_base + 2) * IN_F;
    const int* __restrict__ wr3 = w_q + (size_t)(o_base + 3) * IN_F;

    // Stage chunk c (32 KB: 16 rows x 2048 B) into buf b.
    // Round r: block stages 4 KB; wave stages 1 KB at flat byte
    // f = r*4096 + wave*1024 (+ lane*16 added by HW on the LDS side and
    // explicitly on the global side). Rows are 2048 B, so each wave's 1 KB
    // stays inside one row: global = x + t*32768 + c*2048 + (f&2047).
#define STAGE(c, b)                                                          \
    {                                                                        \
        _Pragma("unroll")                                                    \
        for (int r = 0; r < 8; ++r) {                                        \
            const int f = r * 4096 + wave * 1024 + lane * 16;                \
            const int t = f >> 11;                                           \
            const char* g = (const char*)x + (size_t)t * 32768 +             \
                            (size_t)(c) * 2048 + (f & 2047);                 \
            char* l = (char*)(&xs[0][0][0]) + (b) * 32768 +                  \
                      r * 4096 + wave * 1024;                                \
            __builtin_amdgcn_global_load_lds(                                \
                (const __attribute__((address_space(1))) void*)g,            \
                (__attribute__((address_space(3))) void*)l, 16, 0, 0);       \
        }                                                                    \
    }

    f32x2 acc2[NT][2];   // acc2[t][j2][e] = acc[t][j2*2+e]; 64 VGPRs
#pragma unroll
    for (int t = 0; t < NT; ++t) {
        acc2[t][0] = (f32x2)0.0f;
        acc2[t][1] = (f32x2)0.0f;
    }

    // prologue: stage chunk 0, full wait (nothing older to piggyback on)
    STAGE(0, 0)
    asm volatile("s_waitcnt vmcnt(0)" ::: "memory");
    __builtin_amdgcn_s_barrier();
    __builtin_amdgcn_sched_barrier(0);

#pragma unroll 1
    for (int c = 0; c < NCHUNK; ++c) {
        const int cur = c & 1;

        if (c + 1 < NCHUNK) STAGE(c + 1, cur ^ 1)   // oldest vmem this chunk
        __builtin_amdgcn_sched_barrier(0);

        // ---- compute chunk c: 2 k-steps; w global (vmcnt), x LDS (lgkm) ----
#pragma unroll
        for (int ks = 0; ks < K_CHUNK / 256; ++ks) {
            const int kl = ks * 256 + lane * 4;     // within chunk
            const int kg = c * K_CHUNK + kl;        // global k
            const int4 w0 = *reinterpret_cast<const int4*>(wr0 + kg);
            const int4 w1 = *reinterpret_cast<const int4*>(wr1 + kg);
            const int4 w2 = *reinterpret_cast<const int4*>(wr2 + kg);
            const int4 w3 = *reinterpret_cast<const int4*>(wr3 + kg);

            f32x2 wf[2][4];  // wf[j2][e] = { rows 2*j2, 2*j2+1 } at element e
            wf[0][0] = (f32x2){(float)(w0.x - 128), (float)(w1.x - 128)};
            wf[0][1] = (f32x2){(float)(w0.y - 128), (float)(w1.y - 128)};
            wf[0][2] = (f32x2){(float)(w0.z - 128), (float)(w1.z - 128)};
            wf[0][3] = (f32x2){(float)(w0.w - 128), (float)(w1.w - 128)};
            wf[1][0] = (f32x2){(float)(w2.x - 128), (float)(w3.x - 128)};
            wf[1][1] = (f32x2){(float)(w2.y - 128), (float)(w3.y - 128)};
            wf[1][2] = (f32x2){(float)(w2.z - 128), (float)(w3.z - 128)};
            wf[1][3] = (f32x2){(float)(w2.w - 128), (float)(w3.w - 128)};

#pragma unroll
            for (int t = 0; t < NT; ++t) {
                const float4 xv = *reinterpret_cast<const float4*>(
                    &xs[cur][t][kl]);
                acc2[t][0] += wf[0][0] * (f32x2){xv.x, xv.x};
                acc2[t][1] += wf[1][0] * (f32x2){xv.x, xv.x};
                acc2[t][0] += wf[0][1] * (f32x2){xv.y, xv.y};
                acc2[t][1] += wf[1][1] * (f32x2){xv.y, xv.y};
                acc2[t][0] += wf[0][2] * (f32x2){xv.z, xv.z};
                acc2[t][1] += wf[1][2] * (f32x2){xv.z, xv.z};
                acc2[t][0] += wf[0][3] * (f32x2){xv.w, xv.w};
                acc2[t][1] += wf[1][3] * (f32x2){xv.w, xv.w};
            }
        }

        // barrier: raw, NO vmcnt drain. My ds_reads are consumed (lgkm waits
        // before FMA use); my stage(c+1) retired because chunk-c w-loads
        // (younger, in-order) were consumed above.
        __builtin_amdgcn_sched_barrier(0);
        __builtin_amdgcn_s_barrier();
        __builtin_amdgcn_sched_barrier(0);
    }
#undef STAGE

    // ---- cross-lane reduction: 64 (t,j) values, 6-step butterfly each ----
    float myval = 0.0f;
#pragma unroll
    for (int t = 0; t < NT; ++t) {
#pragma unroll
        for (int j = 0; j < W_O; ++j) {
            float v = acc2[t][j >> 1][j & 1];
#pragma unroll
            for (int off = 32; off > 0; off >>= 1)
                v += __shfl_xor(v, off, 64);
            if (lane == (t * W_O + j)) myval = v;
        }
    }

    // lane l -> (t = l>>2, channel j = l&3)
    const int t_o = lane >> 2;
    const int o   = o_base + (lane & 3);
    out[(size_t)t_o * OUT_F + o] = myval * scale[o] + bias[o];
}

extern "C" void kernel_launch(void* const* d_in, const int* in_sizes, int n_in,
                              void* d_out, int out_size, void* d_ws, size_t ws_size,
                              hipStream_t stream) {
    const float* x     = (const float*)d_in[0];
    const int*   w_q   = (const int*)d_in[1];
    const float* scale = (const float*)d_in[2];
    const float* bias  = (const float*)d_in[3];
    float*       out   = (float*)d_out;

    dim3 grid(OUT_F / CH_PER_BLOCK);   // 512 blocks -> 2 per CU
    dim3 block(BLOCK);
    qlin_kernel<<<grid, block, 0, stream>>>(x, w_q, scale, bias, out);
}